// Round 12
// baseline (562.367 us; speedup 1.0000x reference)
//
#include <hip/hip_runtime.h>
#include <hip/hip_bf16.h>

#define DIMQ 4096
#define NH 32
#define HD 128
#define FFN_D 11008
#define BATCH 8
#define SPQ 2048
#define SEQ 2049           // SP + 1
#define NCH 8              // attention KV chunks per (b,h)
#define LN_THETA 9.210340371976184f  // ln(10000)

// ---------------- RMSNorm: one block per batch row, TRANSPOSED output ----------------
// out layout: [DIMQ][8]  (out[j*8 + b])
__global__ __launch_bounds__(256) void rmsnorm_k(const float* __restrict__ x,
                                                 const float* __restrict__ w,
                                                 float* __restrict__ out) {
    int b = blockIdx.x, tid = threadIdx.x;
    const float* xr = x + b * DIMQ;
    float4 v[4];
    float ss = 0.f;
#pragma unroll
    for (int it = 0; it < 4; ++it) {
        v[it] = *(const float4*)(xr + (it * 256 + tid) * 4);
        ss += v[it].x * v[it].x + v[it].y * v[it].y + v[it].z * v[it].z + v[it].w * v[it].w;
    }
    __shared__ float red[256];
    red[tid] = ss; __syncthreads();
    for (int s = 128; s; s >>= 1) { if (tid < s) red[tid] += red[tid + s]; __syncthreads(); }
    float scale = rsqrtf(red[0] * (1.0f / DIMQ) + 1e-5f);
#pragma unroll
    for (int it = 0; it < 4; ++it) {
        int j = (it * 256 + tid) * 4;
        float4 wv = *(const float4*)(w + j);
        out[(j + 0) * 8 + b] = v[it].x * scale * wv.x;
        out[(j + 1) * 8 + b] = v[it].y * scale * wv.y;
        out[(j + 2) * 8 + b] = v[it].z * scale * wv.z;
        out[(j + 3) * 8 + b] = v[it].w * scale * wv.w;
    }
}

// ---------------- Split-K GEMV partial (float2, unroll 4; TRANSPOSED act input) ----------------
// actT layout: [IN][8]. Staging = coalesced float4 memcpy. Partials: P[(chunk*TOTC + c)*8 + b]
__global__ __launch_bounds__(256) void gemv_part_k(const float* __restrict__ W0,
                                                   const float* __restrict__ W1m,
                                                   const float* __restrict__ W2m,
                                                   int OUT, int IN,
                                                   const float* __restrict__ actT,
                                                   float* __restrict__ P) {
    int tid = threadIdx.x;
    int CH = IN / gridDim.y;
    int i0 = blockIdx.y * CH;
    int TOTC = gridDim.x * 512;
    int effc = blockIdx.x * 512 + tid * 2;
    const float* Wm; int j;
    if (effc < OUT)          { Wm = W0;  j = effc; }
    else if (effc < 2 * OUT) { Wm = W1m; j = effc - OUT; }
    else                     { Wm = W2m; j = effc - 2 * OUT; }
    extern __shared__ float sact[];  // [CH][8]
    int tot4 = (CH * 8) >> 2;
    const float4* src = (const float4*)(actT + (size_t)i0 * 8);
    for (int m = tid; m < tot4; m += 256)
        ((float4*)sact)[m] = src[m];
    __syncthreads();
    float2 acc[8];
#pragma unroll
    for (int bb = 0; bb < 8; ++bb) acc[bb] = make_float2(0.f, 0.f);
    const float* wp = Wm + (size_t)i0 * OUT + j;
#pragma unroll 4
    for (int i = 0; i < CH; ++i) {
        float2 wv = *(const float2*)wp; wp += OUT;
        float4 a0 = *(const float4*)(sact + i * 8);
        float4 a1 = *(const float4*)(sact + i * 8 + 4);
        acc[0].x = fmaf(a0.x, wv.x, acc[0].x); acc[0].y = fmaf(a0.x, wv.y, acc[0].y);
        acc[1].x = fmaf(a0.y, wv.x, acc[1].x); acc[1].y = fmaf(a0.y, wv.y, acc[1].y);
        acc[2].x = fmaf(a0.z, wv.x, acc[2].x); acc[2].y = fmaf(a0.z, wv.y, acc[2].y);
        acc[3].x = fmaf(a0.w, wv.x, acc[3].x); acc[3].y = fmaf(a0.w, wv.y, acc[3].y);
        acc[4].x = fmaf(a1.x, wv.x, acc[4].x); acc[4].y = fmaf(a1.x, wv.y, acc[4].y);
        acc[5].x = fmaf(a1.y, wv.x, acc[5].x); acc[5].y = fmaf(a1.y, wv.y, acc[5].y);
        acc[6].x = fmaf(a1.z, wv.x, acc[6].x); acc[6].y = fmaf(a1.z, wv.y, acc[6].y);
        acc[7].x = fmaf(a1.w, wv.x, acc[7].x); acc[7].y = fmaf(a1.w, wv.y, acc[7].y);
    }
    float* pp = P + ((size_t)blockIdx.y * TOTC + effc) * 8;
    *(float4*)(pp)      = make_float4(acc[0].x, acc[1].x, acc[2].x, acc[3].x);
    *(float4*)(pp + 4)  = make_float4(acc[4].x, acc[5].x, acc[6].x, acc[7].x);
    *(float4*)(pp + 8)  = make_float4(acc[0].y, acc[1].y, acc[2].y, acc[3].y);
    *(float4*)(pp + 12) = make_float4(acc[4].y, acc[5].y, acc[6].y, acc[7].y);
}

// ---------------- Reduce QKV partials + RoPE (2-way chunk split); also zeroes attn counters ----------------
// Outputs q/k/v ROW-major [b][DIMQ] (attention consumes rows).
__global__ __launch_bounds__(256) void reduce_qkv_rope_k(const float* __restrict__ P,
                                                         float* __restrict__ qo,
                                                         float* __restrict__ ko,
                                                         float* __restrict__ vo,
                                                         const int* __restrict__ start_pos,
                                                         int chunks,
                                                         int* __restrict__ cnt) {
    int tid = threadIdx.x;
    if (blockIdx.x == 0) cnt[tid] = 0;        // 256 counters, re-zeroed every call
    int t = blockIdx.x * 128 + (tid & 127);   // < 98304
    int half = tid >> 7;
    int c0 = half * (chunks >> 1);
    int c1 = half ? chunks : (chunks >> 1);
    float s0 = 0.f, s1 = 0.f, s2 = 0.f, s3 = 0.f;
    int ch = c0;
    for (; ch + 4 <= c1; ch += 4) {
        s0 += P[(size_t)(ch + 0) * 98304 + t];
        s1 += P[(size_t)(ch + 1) * 98304 + t];
        s2 += P[(size_t)(ch + 2) * 98304 + t];
        s3 += P[(size_t)(ch + 3) * 98304 + t];
    }
    for (; ch < c1; ++ch) s0 += P[(size_t)ch * 98304 + t];
    float s = s0 + s1 + s2 + s3;
    __shared__ float red[256];
    red[tid] = s; __syncthreads();
    if (tid < 128) {
        s = red[tid] + red[tid + 128];
        float partner = __shfl_xor(s, 8);  // pair column (c^1), same b
        int b = t & 7, ce = t >> 3;
        int mat = ce >> 12, j = ce & 4095;
        if (mat == 2) {
            vo[b * DIMQ + j] = s;
        } else {
            int d = j & (HD - 1), p = d >> 1;
            float freq = __expf(-(float)(2 * p) * (LN_THETA / (float)HD));
            float ang = (float)start_pos[0] * freq;
            float cs = __cosf(ang), sn = __sinf(ang);
            float val = fmaf(s, cs, (j & 1) ? partner * sn : -partner * sn);
            ((mat == 0) ? qo : ko)[b * DIMQ + j] = val;
        }
    }
}

// ---------------- Attention partial + last-block combine ----------------
// One block per (b, head, chunk). The 8th block to finish for a (b,h) performs
// the chunk combine inline (bit-identical order to the old attn_reduce_k).
__global__ __launch_bounds__(256) void attn_part_k(const float* __restrict__ q,
                                                   const float* __restrict__ kn,
                                                   const float* __restrict__ vn,
                                                   const float* __restrict__ ck,
                                                   const float* __restrict__ cv,
                                                   const float* __restrict__ mask,
                                                   float* __restrict__ am,
                                                   float* __restrict__ al,
                                                   float* __restrict__ ao,
                                                   int* __restrict__ cnt,
                                                   float* __restrict__ attnT) {
    int c  = blockIdx.x & (NCH - 1);
    int bh = blockIdx.x >> 3;
    int b = bh >> 5, h = bh & 31;
    int tid = threadIdx.x;
    int t0 = c * 256;
    int t1 = (c == NCH - 1) ? SEQ : t0 + 256;   // last chunk: 257 keys
    __shared__ float sc[257];
    __shared__ float red[256];
    __shared__ float2 pvs[4][64];
    __shared__ int slast;

    int g = tid >> 4, l = tid & 15;
    float qv[8];
    const float* qp = q + b * DIMQ + h * HD + l * 8;
#pragma unroll
    for (int i2 = 0; i2 < 8; ++i2) qv[i2] = qp[i2];
    const float kscale = 0.08838834764831845f;  // 1/sqrt(128)
    const float* mrow = mask + (size_t)(b * NH + h) * SEQ;
    for (int t = t0 + g; t < t1; t += 16) {
        const float* kp = (t < SPQ) ? (ck + ((size_t)(b * SPQ + t) * NH + h) * HD + l * 8)
                                    : (kn + b * DIMQ + h * HD + l * 8);
        float4 k0 = *(const float4*)kp;
        float4 k1 = *(const float4*)(kp + 4);
        float d = qv[0] * k0.x + qv[1] * k0.y + qv[2] * k0.z + qv[3] * k0.w
                + qv[4] * k1.x + qv[5] * k1.y + qv[6] * k1.z + qv[7] * k1.w;
        d += __shfl_xor(d, 1); d += __shfl_xor(d, 2);
        d += __shfl_xor(d, 4); d += __shfl_xor(d, 8);
        if (l == 0) sc[t - t0] = fmaf(d, kscale, mrow[t]);
    }
    __syncthreads();

    int nt = t1 - t0;
    float lm = -1e30f;
    for (int t = tid; t < nt; t += 256) lm = fmaxf(lm, sc[t]);
    red[tid] = lm; __syncthreads();
    for (int s2 = 128; s2; s2 >>= 1) { if (tid < s2) red[tid] = fmaxf(red[tid], red[tid + s2]); __syncthreads(); }
    float m = red[0];
    __syncthreads();
    float ls = 0.f;
    for (int t = tid; t < nt; t += 256) { float p = __expf(sc[t] - m); sc[t] = p; ls += p; }
    red[tid] = ls; __syncthreads();
    for (int s2 = 128; s2; s2 >>= 1) { if (tid < s2) red[tid] += red[tid + s2]; __syncthreads(); }
    float lsum = red[0];

    int dp = tid & 63, q4 = tid >> 6;
    float2 acc = make_float2(0.f, 0.f);
    for (int t = t0 + q4; t < t1; t += 4) {
        float p = sc[t - t0];
        const float* vp = (t < SPQ) ? (cv + ((size_t)(b * SPQ + t) * NH + h) * HD + dp * 2)
                                    : (vn + b * DIMQ + h * HD + dp * 2);
        float2 v2 = *(const float2*)vp;
        acc.x = fmaf(p, v2.x, acc.x);
        acc.y = fmaf(p, v2.y, acc.y);
    }
    pvs[q4][dp] = acc;
    __syncthreads();
    if (tid < 64) {
        float ox = pvs[0][tid].x + pvs[1][tid].x + pvs[2][tid].x + pvs[3][tid].x;
        float oy = pvs[0][tid].y + pvs[1][tid].y + pvs[2][tid].y + pvs[3][tid].y;
        float* op = ao + ((size_t)bh * NCH + c) * HD;
        op[tid * 2]     = ox;
        op[tid * 2 + 1] = oy;
    }
    if (tid == 0) { am[bh * NCH + c] = m; al[bh * NCH + c] = lsum; }

    // ---- last-block-done combine (replaces attn_reduce_k dispatch) ----
    __threadfence();
    if (tid == 0) slast = (atomicAdd(&cnt[bh], 1) == NCH - 1);
    __syncthreads();
    if (slast) {
        __threadfence();
        if (tid < HD) {
            int d = tid;
            float mv[NCH];
            float M = -1e30f;
#pragma unroll
            for (int i = 0; i < NCH; ++i) { mv[i] = am[bh * NCH + i]; M = fmaxf(M, mv[i]); }
            float L = 0.f, a2 = 0.f;
#pragma unroll
            for (int i = 0; i < NCH; ++i) {
                float w = __expf(mv[i] - M);
                L += al[bh * NCH + i] * w;
                a2 += w * ao[((size_t)bh * NCH + i) * HD + d];
            }
            attnT[(h * HD + d) * 8 + b] = a2 / L;   // [DIMQ][8] transposed
        }
    }
}

// ---------------- Reduce partials + residual add (4-way chunk split) ----------------
__global__ __launch_bounds__(256) void reduce_add_k(const float* __restrict__ P,
                                                    const float* __restrict__ resid,
                                                    float* __restrict__ out,
                                                    int chunks, int n) {
    int tid = threadIdx.x;
    int e = blockIdx.x * 64 + (tid & 63);
    int qr = tid >> 6;
    int c0 = (chunks * qr) >> 2;
    int c1 = (chunks * (qr + 1)) >> 2;
    float s0 = 0.f, s1 = 0.f, s2 = 0.f, s3 = 0.f;
    int ch = c0;
    for (; ch + 4 <= c1; ch += 4) {
        s0 += P[(size_t)(ch + 0) * n + e];
        s1 += P[(size_t)(ch + 1) * n + e];
        s2 += P[(size_t)(ch + 2) * n + e];
        s3 += P[(size_t)(ch + 3) * n + e];
    }
    for (; ch < c1; ++ch) s0 += P[(size_t)ch * n + e];
    __shared__ float red[256];
    red[tid] = s0 + s1 + s2 + s3; __syncthreads();
    if (tid < 64) {
        float s = red[tid] + red[tid + 64] + red[tid + 128] + red[tid + 192];
        int b = e & 7, c = e >> 3;
        out[b * DIMQ + c] = resid[b * DIMQ + c] + s;
    }
}

// ---------------- Reduce W1/W3 partials + SiLU*up, TRANSPOSED (sequential) output ----------------
__global__ __launch_bounds__(256) void reduce_silu_k(const float* __restrict__ P,
                                                     float* __restrict__ eT,
                                                     int chunks) {
    int tid = threadIdx.x;
    int t = blockIdx.x * 128 + (tid & 127);   // < 88064
    int half = tid >> 7;
    int c0 = half * (chunks >> 1);
    int c1 = half ? chunks : (chunks >> 1);
    float g0 = 0.f, g1 = 0.f, u0 = 0.f, u1 = 0.f;
    int ch = c0;
    for (; ch + 2 <= c1; ch += 2) {
        g0 += P[(size_t)(ch + 0) * 176128 + t];
        g1 += P[(size_t)(ch + 1) * 176128 + t];
        u0 += P[(size_t)(ch + 0) * 176128 + 88064 + t];
        u1 += P[(size_t)(ch + 1) * 176128 + 88064 + t];
    }
    for (; ch < c1; ++ch) {
        g0 += P[(size_t)ch * 176128 + t];
        u0 += P[(size_t)ch * 176128 + 88064 + t];
    }
    __shared__ float rg[256], ru[256];
    rg[tid] = g0 + g1; ru[tid] = u0 + u1; __syncthreads();
    if (tid < 128) {
        float g = rg[tid] + rg[tid + 128];
        float u = ru[tid] + ru[tid + 128];
        float sg = g / (1.f + __expf(-g));
        eT[t] = sg * u;
    }
}

// ---------------- Launch ----------------
extern "C" void kernel_launch(void* const* d_in, const int* in_sizes, int n_in,
                              void* d_out, int out_size, void* d_ws, size_t ws_size,
                              hipStream_t stream) {
    const float* x      = (const float*)d_in[0];
    const float* ck     = (const float*)d_in[1];
    const float* cv     = (const float*)d_in[2];
    const float* mask   = (const float*)d_in[3];
    const float* wq     = (const float*)d_in[4];
    const float* wk     = (const float*)d_in[5];
    const float* wv     = (const float*)d_in[6];
    const float* wo     = (const float*)d_in[7];
    const float* w1     = (const float*)d_in[8];
    const float* w2     = (const float*)d_in[9];
    const float* w3     = (const float*)d_in[10];
    const float* anw    = (const float*)d_in[11];
    const float* fnw    = (const float*)d_in[12];
    const int*   spos   = (const int*)d_in[13];
    float* out = (float*)d_out;

    float* ws = (float*)d_ws;
    float* hT   = ws;            // 32768  [DIMQ][8]
    float* qb   = ws + 32768;    // [b][DIMQ]
    float* kb   = ws + 65536;
    float* vb   = ws + 98304;
    float* attnT= ws + 131072;   // [DIMQ][8]
    float* x1   = ws + 163840;   // [b][DIMQ]
    float* h2T  = ws + 196608;   // [DIMQ][8]
    float* eT   = ws + 229376;   // 88064  [FFN_D][8]
    float* P    = ws + 317440;   // QKV: 3.15M; W13: 2.82M; W2: 4.19M floats

    float* am = P;               // attention partials reuse P region (stream-ordered;
    float* al = P + 2048;        // QKV partials dead after rope, ao dead before WO gemv)
    float* ao = P + 4096;        // 262144
    int*  cnt = (int*)(P + 4300000);  // 256 counters, past all live partial extents

    // 1. attn rmsnorm -> hT
    rmsnorm_k<<<BATCH, 256, 0, stream>>>(x, anw, hT);
    // 2. QKV GEMV partials: TOTC=12288, 32 chunks (CH=128)
    gemv_part_k<<<dim3(24, 32), 256, 128 * 8 * 4, stream>>>(wq, wk, wv, DIMQ, DIMQ, hT, P);
    // 3. reduce + RoPE (768 blocks); zeroes cnt
    reduce_qkv_rope_k<<<768, 256, 0, stream>>>(P, qb, kb, vb, spos, 32, cnt);
    // 4. attention: flash-decode over 8 chunks, fused last-block combine -> attnT
    attn_part_k<<<BATCH * NH * NCH, 256, 0, stream>>>(qb, kb, vb, ck, cv, mask, am, al, ao, cnt, attnT);
    // 5. WO GEMV partials: TOTC=4096, 64 chunks (CH=64)
    gemv_part_k<<<dim3(8, 64), 256, 64 * 8 * 4, stream>>>(wo, wo, wo, DIMQ, DIMQ, attnT, P);
    // 6. reduce + residual -> x1 (512 blocks)
    reduce_add_k<<<512, 256, 0, stream>>>(P, x, x1, 64, 32768);
    // 7. ffn rmsnorm -> h2T
    rmsnorm_k<<<BATCH, 256, 0, stream>>>(x1, fnw, h2T);
    // 8. W1|W3 GEMV partials: TOTC=22016, 16 chunks (CH=256)
    gemv_part_k<<<dim3(43, 16), 256, 256 * 8 * 4, stream>>>(w1, w3, w3, FFN_D, DIMQ, h2T, P);
    // 9. reduce + silu*up -> eT (688 blocks)
    reduce_silu_k<<<688, 256, 0, stream>>>(P, eT, 16);
    // 10. W2 GEMV partials: TOTC=4096, 128 chunks (CH=86) -> 1024 blocks = 4/CU exact
    gemv_part_k<<<dim3(8, 128), 256, 86 * 8 * 4, stream>>>(w2, w2, w2, DIMQ, FFN_D, eT, P);
    // 11. reduce + residual -> out (512 blocks)
    reduce_add_k<<<512, 256, 0, stream>>>(P, x1, out, 128, 32768);
}

// Round 13
// 287.390 us; speedup vs baseline: 1.9568x; 1.9568x over previous
//
#include <hip/hip_runtime.h>
#include <hip/hip_bf16.h>

#define DIMQ 4096
#define NH 32
#define HD 128
#define FFN_D 11008
#define BATCH 8
#define SPQ 2048
#define SEQ 2049           // SP + 1
#define NCH 8              // attention KV chunks per (b,h)
#define LN_THETA 9.210340371976184f  // ln(10000)

// ---------------- RMSNorm: one block per batch row, TRANSPOSED output ----------------
// out layout: [DIMQ][8]  (out[j*8 + b])
__global__ __launch_bounds__(256) void rmsnorm_k(const float* __restrict__ x,
                                                 const float* __restrict__ w,
                                                 float* __restrict__ out) {
    int b = blockIdx.x, tid = threadIdx.x;
    const float* xr = x + b * DIMQ;
    float4 v[4];
    float ss = 0.f;
#pragma unroll
    for (int it = 0; it < 4; ++it) {
        v[it] = *(const float4*)(xr + (it * 256 + tid) * 4);
        ss += v[it].x * v[it].x + v[it].y * v[it].y + v[it].z * v[it].z + v[it].w * v[it].w;
    }
    __shared__ float red[256];
    red[tid] = ss; __syncthreads();
    for (int s = 128; s; s >>= 1) { if (tid < s) red[tid] += red[tid + s]; __syncthreads(); }
    float scale = rsqrtf(red[0] * (1.0f / DIMQ) + 1e-5f);
#pragma unroll
    for (int it = 0; it < 4; ++it) {
        int j = (it * 256 + tid) * 4;
        float4 wv = *(const float4*)(w + j);
        out[(j + 0) * 8 + b] = v[it].x * scale * wv.x;
        out[(j + 1) * 8 + b] = v[it].y * scale * wv.y;
        out[(j + 2) * 8 + b] = v[it].z * scale * wv.z;
        out[(j + 3) * 8 + b] = v[it].w * scale * wv.w;
    }
}

// ---------------- Split-K GEMV partial (float2, unroll 4; TRANSPOSED act input) ----------------
// actT layout: [IN][8]. Staging = coalesced float4 memcpy. Partials: P[(chunk*TOTC + c)*8 + b]
__global__ __launch_bounds__(256) void gemv_part_k(const float* __restrict__ W0,
                                                   const float* __restrict__ W1m,
                                                   const float* __restrict__ W2m,
                                                   int OUT, int IN,
                                                   const float* __restrict__ actT,
                                                   float* __restrict__ P) {
    int tid = threadIdx.x;
    int CH = IN / gridDim.y;
    int i0 = blockIdx.y * CH;
    int TOTC = gridDim.x * 512;
    int effc = blockIdx.x * 512 + tid * 2;
    const float* Wm; int j;
    if (effc < OUT)          { Wm = W0;  j = effc; }
    else if (effc < 2 * OUT) { Wm = W1m; j = effc - OUT; }
    else                     { Wm = W2m; j = effc - 2 * OUT; }
    extern __shared__ float sact[];  // [CH][8]
    int tot4 = (CH * 8) >> 2;
    const float4* src = (const float4*)(actT + (size_t)i0 * 8);
    for (int m = tid; m < tot4; m += 256)
        ((float4*)sact)[m] = src[m];
    __syncthreads();
    float2 acc[8];
#pragma unroll
    for (int bb = 0; bb < 8; ++bb) acc[bb] = make_float2(0.f, 0.f);
    const float* wp = Wm + (size_t)i0 * OUT + j;
#pragma unroll 4
    for (int i = 0; i < CH; ++i) {
        float2 wv = *(const float2*)wp; wp += OUT;
        float4 a0 = *(const float4*)(sact + i * 8);
        float4 a1 = *(const float4*)(sact + i * 8 + 4);
        acc[0].x = fmaf(a0.x, wv.x, acc[0].x); acc[0].y = fmaf(a0.x, wv.y, acc[0].y);
        acc[1].x = fmaf(a0.y, wv.x, acc[1].x); acc[1].y = fmaf(a0.y, wv.y, acc[1].y);
        acc[2].x = fmaf(a0.z, wv.x, acc[2].x); acc[2].y = fmaf(a0.z, wv.y, acc[2].y);
        acc[3].x = fmaf(a0.w, wv.x, acc[3].x); acc[3].y = fmaf(a0.w, wv.y, acc[3].y);
        acc[4].x = fmaf(a1.x, wv.x, acc[4].x); acc[4].y = fmaf(a1.x, wv.y, acc[4].y);
        acc[5].x = fmaf(a1.y, wv.x, acc[5].x); acc[5].y = fmaf(a1.y, wv.y, acc[5].y);
        acc[6].x = fmaf(a1.z, wv.x, acc[6].x); acc[6].y = fmaf(a1.z, wv.y, acc[6].y);
        acc[7].x = fmaf(a1.w, wv.x, acc[7].x); acc[7].y = fmaf(a1.w, wv.y, acc[7].y);
    }
    float* pp = P + ((size_t)blockIdx.y * TOTC + effc) * 8;
    *(float4*)(pp)      = make_float4(acc[0].x, acc[1].x, acc[2].x, acc[3].x);
    *(float4*)(pp + 4)  = make_float4(acc[4].x, acc[5].x, acc[6].x, acc[7].x);
    *(float4*)(pp + 8)  = make_float4(acc[0].y, acc[1].y, acc[2].y, acc[3].y);
    *(float4*)(pp + 12) = make_float4(acc[4].y, acc[5].y, acc[6].y, acc[7].y);
}

// ---------------- Reduce QKV partials + RoPE (2-way chunk split) ----------------
// Outputs q/k/v ROW-major [b][DIMQ] (attention consumes rows).
__global__ __launch_bounds__(256) void reduce_qkv_rope_k(const float* __restrict__ P,
                                                         float* __restrict__ qo,
                                                         float* __restrict__ ko,
                                                         float* __restrict__ vo,
                                                         const int* __restrict__ start_pos,
                                                         int chunks) {
    int tid = threadIdx.x;
    int t = blockIdx.x * 128 + (tid & 127);   // < 98304
    int half = tid >> 7;
    int c0 = half * (chunks >> 1);
    int c1 = half ? chunks : (chunks >> 1);
    float s0 = 0.f, s1 = 0.f, s2 = 0.f, s3 = 0.f;
    int ch = c0;
    for (; ch + 4 <= c1; ch += 4) {
        s0 += P[(size_t)(ch + 0) * 98304 + t];
        s1 += P[(size_t)(ch + 1) * 98304 + t];
        s2 += P[(size_t)(ch + 2) * 98304 + t];
        s3 += P[(size_t)(ch + 3) * 98304 + t];
    }
    for (; ch < c1; ++ch) s0 += P[(size_t)ch * 98304 + t];
    float s = s0 + s1 + s2 + s3;
    __shared__ float red[256];
    red[tid] = s; __syncthreads();
    if (tid < 128) {
        s = red[tid] + red[tid + 128];
        float partner = __shfl_xor(s, 8);  // pair column (c^1), same b
        int b = t & 7, ce = t >> 3;
        int mat = ce >> 12, j = ce & 4095;
        if (mat == 2) {
            vo[b * DIMQ + j] = s;
        } else {
            int d = j & (HD - 1), p = d >> 1;
            float freq = __expf(-(float)(2 * p) * (LN_THETA / (float)HD));
            float ang = (float)start_pos[0] * freq;
            float cs = __cosf(ang), sn = __sinf(ang);
            float val = fmaf(s, cs, (j & 1) ? partner * sn : -partner * sn);
            ((mat == 0) ? qo : ko)[b * DIMQ + j] = val;
        }
    }
}

// ---------------- Attention partial: one block per (b, head, chunk) ----------------
__global__ __launch_bounds__(256) void attn_part_k(const float* __restrict__ q,
                                                   const float* __restrict__ kn,
                                                   const float* __restrict__ vn,
                                                   const float* __restrict__ ck,
                                                   const float* __restrict__ cv,
                                                   const float* __restrict__ mask,
                                                   float* __restrict__ am,
                                                   float* __restrict__ al,
                                                   float* __restrict__ ao) {
    int c  = blockIdx.x & (NCH - 1);
    int bh = blockIdx.x >> 3;
    int b = bh >> 5, h = bh & 31;
    int tid = threadIdx.x;
    int t0 = c * 256;
    int t1 = (c == NCH - 1) ? SEQ : t0 + 256;   // last chunk: 257 keys
    __shared__ float sc[257];
    __shared__ float red[256];
    __shared__ float2 pvs[4][64];

    int g = tid >> 4, l = tid & 15;
    float qv[8];
    const float* qp = q + b * DIMQ + h * HD + l * 8;
#pragma unroll
    for (int i2 = 0; i2 < 8; ++i2) qv[i2] = qp[i2];
    const float kscale = 0.08838834764831845f;  // 1/sqrt(128)
    const float* mrow = mask + (size_t)(b * NH + h) * SEQ;
    for (int t = t0 + g; t < t1; t += 16) {
        const float* kp = (t < SPQ) ? (ck + ((size_t)(b * SPQ + t) * NH + h) * HD + l * 8)
                                    : (kn + b * DIMQ + h * HD + l * 8);
        float4 k0 = *(const float4*)kp;
        float4 k1 = *(const float4*)(kp + 4);
        float d = qv[0] * k0.x + qv[1] * k0.y + qv[2] * k0.z + qv[3] * k0.w
                + qv[4] * k1.x + qv[5] * k1.y + qv[6] * k1.z + qv[7] * k1.w;
        d += __shfl_xor(d, 1); d += __shfl_xor(d, 2);
        d += __shfl_xor(d, 4); d += __shfl_xor(d, 8);
        if (l == 0) sc[t - t0] = fmaf(d, kscale, mrow[t]);
    }
    __syncthreads();

    int nt = t1 - t0;
    float lm = -1e30f;
    for (int t = tid; t < nt; t += 256) lm = fmaxf(lm, sc[t]);
    red[tid] = lm; __syncthreads();
    for (int s2 = 128; s2; s2 >>= 1) { if (tid < s2) red[tid] = fmaxf(red[tid], red[tid + s2]); __syncthreads(); }
    float m = red[0];
    __syncthreads();
    float ls = 0.f;
    for (int t = tid; t < nt; t += 256) { float p = __expf(sc[t] - m); sc[t] = p; ls += p; }
    red[tid] = ls; __syncthreads();
    for (int s2 = 128; s2; s2 >>= 1) { if (tid < s2) red[tid] += red[tid + s2]; __syncthreads(); }
    float lsum = red[0];

    int dp = tid & 63, q4 = tid >> 6;
    float2 acc = make_float2(0.f, 0.f);
    for (int t = t0 + q4; t < t1; t += 4) {
        float p = sc[t - t0];
        const float* vp = (t < SPQ) ? (cv + ((size_t)(b * SPQ + t) * NH + h) * HD + dp * 2)
                                    : (vn + b * DIMQ + h * HD + dp * 2);
        float2 v2 = *(const float2*)vp;
        acc.x = fmaf(p, v2.x, acc.x);
        acc.y = fmaf(p, v2.y, acc.y);
    }
    pvs[q4][dp] = acc;
    __syncthreads();
    if (tid < 64) {
        float ox = pvs[0][tid].x + pvs[1][tid].x + pvs[2][tid].x + pvs[3][tid].x;
        float oy = pvs[0][tid].y + pvs[1][tid].y + pvs[2][tid].y + pvs[3][tid].y;
        float* op = ao + ((size_t)bh * NCH + c) * HD;
        op[tid * 2]     = ox;
        op[tid * 2 + 1] = oy;
    }
    if (tid == 0) { am[bh * NCH + c] = m; al[bh * NCH + c] = lsum; }
}

// ---------------- Attention reduce: combine NCH chunks, TRANSPOSED output ----------------
// outT layout: [DIMQ][8]  (outT[(h*HD+d)*8 + b])
__global__ __launch_bounds__(128) void attn_reduce_k(const float* __restrict__ am,
                                                     const float* __restrict__ al,
                                                     const float* __restrict__ ao,
                                                     float* __restrict__ outT) {
    int bh = blockIdx.x;        // 0..255
    int b = bh >> 5, h = bh & 31;
    int d = threadIdx.x;        // 0..127
    float mv[NCH];
    float M = -1e30f;
#pragma unroll
    for (int i = 0; i < NCH; ++i) { mv[i] = am[bh * NCH + i]; M = fmaxf(M, mv[i]); }
    float L = 0.f, acc = 0.f;
#pragma unroll
    for (int i = 0; i < NCH; ++i) {
        float w = __expf(mv[i] - M);
        L += al[bh * NCH + i] * w;
        acc += w * ao[((size_t)bh * NCH + i) * HD + d];
    }
    outT[(h * HD + d) * 8 + b] = acc / L;
}

// ---------------- Reduce partials + residual add (4-way chunk split) ----------------
// resid/out ROW-major [b][DIMQ] (residual stream layout; final d_out layout).
__global__ __launch_bounds__(256) void reduce_add_k(const float* __restrict__ P,
                                                    const float* __restrict__ resid,
                                                    float* __restrict__ out,
                                                    int chunks, int n) {
    int tid = threadIdx.x;
    int e = blockIdx.x * 64 + (tid & 63);
    int qr = tid >> 6;
    int c0 = (chunks * qr) >> 2;
    int c1 = (chunks * (qr + 1)) >> 2;
    float s0 = 0.f, s1 = 0.f, s2 = 0.f, s3 = 0.f;
    int ch = c0;
    for (; ch + 4 <= c1; ch += 4) {
        s0 += P[(size_t)(ch + 0) * n + e];
        s1 += P[(size_t)(ch + 1) * n + e];
        s2 += P[(size_t)(ch + 2) * n + e];
        s3 += P[(size_t)(ch + 3) * n + e];
    }
    for (; ch < c1; ++ch) s0 += P[(size_t)ch * n + e];
    __shared__ float red[256];
    red[tid] = s0 + s1 + s2 + s3; __syncthreads();
    if (tid < 64) {
        float s = red[tid] + red[tid + 64] + red[tid + 128] + red[tid + 192];
        int b = e & 7, c = e >> 3;
        out[b * DIMQ + c] = resid[b * DIMQ + c] + s;
    }
}

// ---------------- Reduce W1/W3 partials + SiLU*up, TRANSPOSED (sequential!) output ----------------
// eT layout: [FFN_D][8]; element index t == c*8+b, so the store is fully coalesced.
__global__ __launch_bounds__(256) void reduce_silu_k(const float* __restrict__ P,
                                                     float* __restrict__ eT,
                                                     int chunks) {
    int tid = threadIdx.x;
    int t = blockIdx.x * 128 + (tid & 127);   // < 88064
    int half = tid >> 7;
    int c0 = half * (chunks >> 1);
    int c1 = half ? chunks : (chunks >> 1);
    float g0 = 0.f, g1 = 0.f, u0 = 0.f, u1 = 0.f;
    int ch = c0;
    for (; ch + 2 <= c1; ch += 2) {
        g0 += P[(size_t)(ch + 0) * 176128 + t];
        g1 += P[(size_t)(ch + 1) * 176128 + t];
        u0 += P[(size_t)(ch + 0) * 176128 + 88064 + t];
        u1 += P[(size_t)(ch + 1) * 176128 + 88064 + t];
    }
    for (; ch < c1; ++ch) {
        g0 += P[(size_t)ch * 176128 + t];
        u0 += P[(size_t)ch * 176128 + 88064 + t];
    }
    __shared__ float rg[256], ru[256];
    rg[tid] = g0 + g1; ru[tid] = u0 + u1; __syncthreads();
    if (tid < 128) {
        float g = rg[tid] + rg[tid + 128];
        float u = ru[tid] + ru[tid + 128];
        float sg = g / (1.f + __expf(-g));
        eT[t] = sg * u;
    }
}

// ---------------- Launch ----------------
extern "C" void kernel_launch(void* const* d_in, const int* in_sizes, int n_in,
                              void* d_out, int out_size, void* d_ws, size_t ws_size,
                              hipStream_t stream) {
    const float* x      = (const float*)d_in[0];
    const float* ck     = (const float*)d_in[1];
    const float* cv     = (const float*)d_in[2];
    const float* mask   = (const float*)d_in[3];
    const float* wq     = (const float*)d_in[4];
    const float* wk     = (const float*)d_in[5];
    const float* wv     = (const float*)d_in[6];
    const float* wo     = (const float*)d_in[7];
    const float* w1     = (const float*)d_in[8];
    const float* w2     = (const float*)d_in[9];
    const float* w3     = (const float*)d_in[10];
    const float* anw    = (const float*)d_in[11];
    const float* fnw    = (const float*)d_in[12];
    const int*   spos   = (const int*)d_in[13];
    float* out = (float*)d_out;

    float* ws = (float*)d_ws;
    float* hT   = ws;            // 32768  [DIMQ][8]
    float* qb   = ws + 32768;    // [b][DIMQ]
    float* kb   = ws + 65536;
    float* vb   = ws + 98304;
    float* attnT= ws + 131072;   // [DIMQ][8]
    float* x1   = ws + 163840;   // [b][DIMQ]
    float* h2T  = ws + 196608;   // [DIMQ][8]
    float* eT   = ws + 229376;   // 88064  [FFN_D][8]
    float* P    = ws + 317440;   // up to 3,145,728 floats (~13.9 MB total)

    float* am = P;               // attention partials reuse P region (stream-ordered;
    float* al = P + 2048;        // QKV partials dead after rope, ao dead before WO gemv)
    float* ao = P + 4096;        // 262144

    // 1. attn rmsnorm -> hT
    rmsnorm_k<<<BATCH, 256, 0, stream>>>(x, anw, hT);
    // 2. QKV GEMV partials: TOTC=12288, 32 chunks (CH=128)
    gemv_part_k<<<dim3(24, 32), 256, 128 * 8 * 4, stream>>>(wq, wk, wv, DIMQ, DIMQ, hT, P);
    // 3. reduce + RoPE (768 blocks)
    reduce_qkv_rope_k<<<768, 256, 0, stream>>>(P, qb, kb, vb, spos, 32);
    // 4. attention: flash-decode over 8 chunks, then combine -> attnT
    attn_part_k<<<BATCH * NH * NCH, 256, 0, stream>>>(qb, kb, vb, ck, cv, mask, am, al, ao);
    attn_reduce_k<<<BATCH * NH, 128, 0, stream>>>(am, al, ao, attnT);
    // 5. WO GEMV partials: TOTC=4096, 64 chunks (CH=64)
    gemv_part_k<<<dim3(8, 64), 256, 64 * 8 * 4, stream>>>(wo, wo, wo, DIMQ, DIMQ, attnT, P);
    // 6. reduce + residual -> x1 (512 blocks)
    reduce_add_k<<<512, 256, 0, stream>>>(P, x, x1, 64, 32768);
    // 7. ffn rmsnorm -> h2T
    rmsnorm_k<<<BATCH, 256, 0, stream>>>(x1, fnw, h2T);
    // 8. W1|W3 GEMV partials: TOTC=22016, 16 chunks (CH=256)
    gemv_part_k<<<dim3(43, 16), 256, 256 * 8 * 4, stream>>>(w1, w3, w3, FFN_D, DIMQ, h2T, P);
    // 9. reduce + silu*up -> eT (688 blocks)
    reduce_silu_k<<<688, 256, 0, stream>>>(P, eT, 16);
    // 10. W2 GEMV partials: TOTC=4096, 86 chunks (CH=128)
    gemv_part_k<<<dim3(8, 86), 256, 128 * 8 * 4, stream>>>(w2, w2, w2, DIMQ, FFN_D, eT, P);
    // 11. reduce + residual -> out (512 blocks)
    reduce_add_k<<<512, 256, 0, stream>>>(P, x1, out, 86, 32768);
}